// Round 3
// baseline (735.858 us; speedup 1.0000x reference)
//
#include <hip/hip_runtime.h>

#define B_  2
#define NQ  2048
#define NK  2048
#define C_  256
#define H_  8
#define HD  32
#define SPLIT 4
#define KSEG (NK / SPLIT)          // 512 keys per WG
#define KT   (KSEG / 32)           // 16 tiles of 32 keys
#define QT_  (NQ / 16)             // 128 q-tiles
#define PART_STRIDE 544            // 512 O + 16 m + 16 l (f32)

typedef float f32x4 __attribute__((ext_vector_type(4)));
typedef __bf16 bf16x8 __attribute__((ext_vector_type(8)));
typedef unsigned short ushort8 __attribute__((ext_vector_type(8)));

// f32 -> bf16 round-to-nearest-even
static __device__ __forceinline__ unsigned short f2bf(float f) {
    unsigned int u = __builtin_bit_cast(unsigned int, f);
    u += 0x7FFFu + ((u >> 16) & 1u);
    return (unsigned short)(u >> 16);
}
static __device__ __forceinline__ float bf2f(unsigned short h) {
    unsigned int u = ((unsigned int)h) << 16;
    return __builtin_bit_cast(float, u);
}
// split f32 -> (hi bf16 in low 16, lo bf16 in high 16); hi+lo ~ f to 2^-19 rel
static __device__ __forceinline__ unsigned int split1(float f) {
    unsigned short h = f2bf(f);
    unsigned short l = f2bf(f - bf2f(h));
    return (unsigned int)h | ((unsigned int)l << 16);
}
static __device__ __forceinline__ bf16x8 ld_bf16x8(const unsigned short* p) {
    return __builtin_bit_cast(bf16x8, *(const ushort8*)p);
}

// raw workgroup barrier: LDS flush only, NO vmcnt drain (keeps global loads
// in flight across the barrier). m201-verified pattern, sched-pinned.
static __device__ __forceinline__ void barrier_lds() {
    __builtin_amdgcn_sched_barrier(0);
    asm volatile("s_waitcnt lgkmcnt(0)" ::: "memory");
    __builtin_amdgcn_s_barrier();
    __builtin_amdgcn_sched_barrier(0);
}

// ---------------------------------------------------------------------------
// Pack mask (int32 [NQ][NK]) into per-qtile bitmasks: maskb[qt][k] bit q = mask.
// ---------------------------------------------------------------------------
__global__ __launch_bounds__(256) void maskpack_kernel(const int* __restrict__ mask,
                                                       unsigned short* __restrict__ mb)
{
    const int qt = blockIdx.x;
    const int k  = blockIdx.y * 256 + threadIdx.x;
    unsigned int m = 0;
    #pragma unroll
    for (int r = 0; r < 16; ++r)
        m |= (mask[(size_t)(qt * 16 + r) * NK + k] ? 1u : 0u) << r;
    mb[(size_t)qt * NK + k] = (unsigned short)m;
}

// ---------------------------------------------------------------------------
// Fused Q/K/V projection GEMM (split-bf16 4-term MFMA), selected by blockIdx.z.
// z=0: Q (row layout)  z=1: K (row layout)  z=2: V (transposed layout)
// grid (64,4,3), block 256 (4 waves); tile 64x64, K-step 32.
// ---------------------------------------------------------------------------
__global__ __launch_bounds__(256) void proj_kernel(
        const float* __restrict__ query, const float* __restrict__ key,
        const float* __restrict__ value,
        const float* __restrict__ Wq, const float* __restrict__ Wk,
        const float* __restrict__ Wv,
        unsigned short* __restrict__ qbh, unsigned short* __restrict__ qbl,
        unsigned short* __restrict__ kbh, unsigned short* __restrict__ kbl,
        unsigned short* __restrict__ vbh, unsigned short* __restrict__ vbl)
{
    __shared__ unsigned short WtH[64][40];
    __shared__ unsigned short WtL[64][40];

    const int z = blockIdx.z;
    const float* X = (z == 0) ? query : (z == 1) ? key : value;
    const float* W = (z == 0) ? Wq    : (z == 1) ? Wk  : Wv;
    unsigned short* dh = (z == 0) ? qbh : (z == 1) ? kbh : vbh;
    unsigned short* dl = (z == 0) ? qbl : (z == 1) ? kbl : vbl;
    const int vmode = (z == 2);

    const int tid  = threadIdx.x;
    const int wave = tid >> 6;
    const int lane = tid & 63;
    const int n15  = lane & 15;
    const int quad = lane >> 4;
    const int m0   = blockIdx.x * 64;
    const int j0   = blockIdx.y * 64;

    f32x4 acc[4];
    acc[0] = 0.f; acc[1] = 0.f; acc[2] = 0.f; acc[3] = 0.f;

    const int sj  = tid >> 2;
    const int skc = (tid & 3) * 8;
    const float* __restrict__ xrow = X + (size_t)(m0 + wave * 16 + n15) * C_;

    for (int k0 = 0; k0 < C_; k0 += 32) {
        ushort8 wh, wl;
        #pragma unroll
        for (int i = 0; i < 8; ++i) {
            unsigned int p = split1(W[(size_t)(k0 + skc + i) * C_ + j0 + sj]);
            wh[i] = (unsigned short)p;
            wl[i] = (unsigned short)(p >> 16);
        }
        *(ushort8*)&WtH[sj][skc] = wh;
        *(ushort8*)&WtL[sj][skc] = wl;
        __syncthreads();

        f32x4 a0 = *(const f32x4*)(xrow + k0 + quad * 8);
        f32x4 a1 = *(const f32x4*)(xrow + k0 + quad * 8 + 4);
        ushort8 ah, al;
        #pragma unroll
        for (int i = 0; i < 4; ++i) {
            unsigned int p0 = split1(a0[i]);
            unsigned int p1 = split1(a1[i]);
            ah[i]     = (unsigned short)p0;  al[i]     = (unsigned short)(p0 >> 16);
            ah[i + 4] = (unsigned short)p1;  al[i + 4] = (unsigned short)(p1 >> 16);
        }
        bf16x8 Ah = __builtin_bit_cast(bf16x8, ah);
        bf16x8 Al = __builtin_bit_cast(bf16x8, al);

        #pragma unroll
        for (int f = 0; f < 4; ++f) {
            bf16x8 Bh = ld_bf16x8(&WtH[f * 16 + n15][quad * 8]);
            bf16x8 Bl = ld_bf16x8(&WtL[f * 16 + n15][quad * 8]);
            acc[f] = __builtin_amdgcn_mfma_f32_16x16x32_bf16(Al, Bl, acc[f], 0, 0, 0);
            acc[f] = __builtin_amdgcn_mfma_f32_16x16x32_bf16(Al, Bh, acc[f], 0, 0, 0);
            acc[f] = __builtin_amdgcn_mfma_f32_16x16x32_bf16(Ah, Bl, acc[f], 0, 0, 0);
            acc[f] = __builtin_amdgcn_mfma_f32_16x16x32_bf16(Ah, Bh, acc[f], 0, 0, 0);
        }
        __syncthreads();
    }

    #pragma unroll
    for (int f = 0; f < 4; ++f) {
        const int j = j0 + f * 16 + n15;
        const int h = j >> 5, dd = j & 31;
        #pragma unroll
        for (int r = 0; r < 4; ++r) {
            const int grow = m0 + wave * 16 + quad * 4 + r;
            const int b = grow >> 11, row = grow & 2047;
            unsigned int p = split1(acc[f][r]);
            size_t idx;
            if (vmode) idx = (size_t)((b * H_ + h) * HD + dd) * NK + row;
            else       idx = (size_t)((b * H_ + h) * NK + row) * HD + dd;
            dh[idx] = (unsigned short)p;
            dl[idx] = (unsigned short)(p >> 16);
        }
    }
}

// ---------------------------------------------------------------------------
// Output projection: out[m,j] = sum_k x[m,k]*Wp[k,j] + bp[j], f32 out.
// ---------------------------------------------------------------------------
__global__ __launch_bounds__(256) void outproj_kernel(const unsigned short* __restrict__ Xh,
                                                      const unsigned short* __restrict__ Xl,
                                                      const float* __restrict__ W,
                                                      const float* __restrict__ bias,
                                                      float* __restrict__ out)
{
    __shared__ unsigned short WtH[64][40];
    __shared__ unsigned short WtL[64][40];

    const int tid  = threadIdx.x;
    const int wave = tid >> 6;
    const int lane = tid & 63;
    const int n15  = lane & 15;
    const int quad = lane >> 4;
    const int m0   = blockIdx.x * 64;
    const int j0   = blockIdx.y * 64;

    f32x4 acc[4];
    acc[0] = 0.f; acc[1] = 0.f; acc[2] = 0.f; acc[3] = 0.f;

    const int sj  = tid >> 2;
    const int skc = (tid & 3) * 8;
    const size_t xoff = (size_t)(m0 + wave * 16 + n15) * C_;

    for (int k0 = 0; k0 < C_; k0 += 32) {
        ushort8 wh, wl;
        #pragma unroll
        for (int i = 0; i < 8; ++i) {
            unsigned int p = split1(W[(size_t)(k0 + skc + i) * C_ + j0 + sj]);
            wh[i] = (unsigned short)p;
            wl[i] = (unsigned short)(p >> 16);
        }
        *(ushort8*)&WtH[sj][skc] = wh;
        *(ushort8*)&WtL[sj][skc] = wl;
        __syncthreads();

        bf16x8 Ah = ld_bf16x8(Xh + xoff + k0 + quad * 8);
        bf16x8 Al = ld_bf16x8(Xl + xoff + k0 + quad * 8);

        #pragma unroll
        for (int f = 0; f < 4; ++f) {
            bf16x8 Bh = ld_bf16x8(&WtH[f * 16 + n15][quad * 8]);
            bf16x8 Bl = ld_bf16x8(&WtL[f * 16 + n15][quad * 8]);
            acc[f] = __builtin_amdgcn_mfma_f32_16x16x32_bf16(Al, Bl, acc[f], 0, 0, 0);
            acc[f] = __builtin_amdgcn_mfma_f32_16x16x32_bf16(Al, Bh, acc[f], 0, 0, 0);
            acc[f] = __builtin_amdgcn_mfma_f32_16x16x32_bf16(Ah, Bl, acc[f], 0, 0, 0);
            acc[f] = __builtin_amdgcn_mfma_f32_16x16x32_bf16(Ah, Bh, acc[f], 0, 0, 0);
        }
        __syncthreads();
    }

    #pragma unroll
    for (int f = 0; f < 4; ++f) {
        const int j = j0 + f * 16 + n15;
        const float bj = bias[j];
        #pragma unroll
        for (int r = 0; r < 4; ++r) {
            const int grow = m0 + wave * 16 + quad * 4 + r;
            out[(size_t)grow * C_ + j] = acc[f][r] + bj;
        }
    }
}

// ---------------------------------------------------------------------------
// Flash attention, split-K x4. grid 1024; block 512. Wave w == head w.
// XCD swizzle: bid = qt*8 + (s*2+b); round-robin bid%8 -> XCD, so all 128
// qt-WGs sharing one (s,b) K/V slice (1 MB) live on one XCD's 4MB L2.
// sim path: REGISTER staging (no global_load_lds -- that path double-fetched
// from HBM when left in flight, R2 evidence). Per tile:
//   [K/V-K loads oldest | mask next | sim(t+1) newest]   (issue order pinned)
//   raw barrier (lgkm only, NO vmcnt drain)  -> bias phase -> raw barrier
//   body: S-MFMA waits K (counted, sim stays in flight), V loads mid-body,
//   softmax, P->LDS->A-frag, O-MFMA; then ds_write sim(t+1) regs -> LDS.
// sim loads are in flight for ~a full tile; no barrier ever drains vmcnt.
// LDS 46 KB -> 3 WGs/CU.
// ---------------------------------------------------------------------------
__global__ __launch_bounds__(512, 6) void attn_kernel(
        const unsigned short* __restrict__ qh, const unsigned short* __restrict__ ql,
        const unsigned short* __restrict__ kh, const unsigned short* __restrict__ kl,
        const unsigned short* __restrict__ vh, const unsigned short* __restrict__ vl,
        const float* __restrict__ sim, const unsigned short* __restrict__ maskb,
        float* __restrict__ part)
{
    __shared__ __align__(16) float simLds[2][H_][16][33];       // 33.8 KB (padded)
    __shared__ float biasLds[16][33];                           // 2.1 KB
    __shared__ __align__(16) unsigned short pLds[H_][16 * 40];  // 10 KB

    const int tid  = threadIdx.x;
    const int wave = tid >> 6;    // head
    const int lane = tid & 63;
    const int n15  = lane & 15;
    const int quad = lane >> 4;

    const int wg = blockIdx.x;
    const int qt = wg >> 3;            // 0..127
    const int sb = wg & 7;             // XCD id under round-robin dispatch
    const int s  = sb >> 1;            // key split 0..3
    const int b  = sb & 1;
    const int q0 = qt * 16;
    const int kbeg = s * KSEG;

    const size_t bh   = (size_t)(b * H_ + wave);
    const size_t qoff = (bh * NQ + q0 + n15) * HD + quad * 8;
    const unsigned short* khb = kh + bh * NK * HD;
    const unsigned short* klb = kl + bh * NK * HD;
    const unsigned short* vhb = vh + bh * HD * NK;
    const unsigned short* vlb = vl + bh * HD * NK;
    const unsigned short* mkb = maskb + (size_t)qt * NK + kbeg;

    // sim reg-staging mapping: lane covers row=lane>>2 (16 rows), 8 f32 at
    // col (lane&3)*8 -- 128B contiguous per 4 lanes, two dwordx4 per lane.
    const int swr = lane >> 2, swc = (lane & 3) * 8;
    const float* gsim = sim + (bh * NQ + q0 + swr) * (size_t)NK + kbeg + swc;
    const int kk = tid & 31;           // bias-phase column

    const bf16x8 Qh = ld_bf16x8(qh + qoff);
    const bf16x8 Ql = ld_bf16x8(ql + qoff);

    f32x4 O0 = 0.f, O1 = 0.f;
    float m_r[4] = {0.f, 0.f, 0.f, 0.f};   // m-floor 0 (scores << 88, safe)
    float l_r[4] = {0.f, 0.f, 0.f, 0.f};

    const float scale = 0.17677669529663687f;  // 1/sqrt(32)

    // prologue: tile-0 sim -> regs -> LDS buffer 0; tile-0 mask bits
    {
        f32x4 pA = *(const f32x4*)gsim;
        f32x4 pB = *(const f32x4*)(gsim + 4);
        float* sw0 = &simLds[0][wave][swr][swc];
        *(f32x4*)sw0       = pA;       // compiler inserts vmcnt wait here
        *(f32x4*)(sw0 + 4) = pB;
    }
    unsigned short mcur = mkb[kk];

    for (int it = 0; it < KT - 1; ++it) {
        const int k0  = kbeg + it * 32;
        const int cur = it & 1;

        // ---- VMEM issue, oldest->newest: K, mask(t+1), sim(t+1) ----
        const size_t koA = (size_t)(k0 + n15) * HD + quad * 8;
        const size_t koB = (size_t)(k0 + 16 + n15) * HD + quad * 8;
        bf16x8 Kh0 = ld_bf16x8(khb + koA), Kl0 = ld_bf16x8(klb + koA);
        bf16x8 Kh1 = ld_bf16x8(khb + koB), Kl1 = ld_bf16x8(klb + koB);
        const unsigned short mnext = mkb[(it + 1) * 32 + kk];
        __builtin_amdgcn_sched_barrier(0);
        f32x4 nA = *(const f32x4*)(gsim + (it + 1) * 32);
        f32x4 nB = *(const f32x4*)(gsim + (it + 1) * 32 + 4);
        __builtin_amdgcn_sched_barrier(0);

        barrier_lds();  // B1: simLds[cur] (tile it, written end of prev tile) visible

        {   // mean-over-heads + packed mask -> biasLds
            const int qq = tid >> 5;
            float sum = 0.f;
            #pragma unroll
            for (int h = 0; h < H_; ++h) sum += simLds[cur][h][qq][kk];
            biasLds[qq][kk] = ((mcur >> qq) & 1) ? (-0.125f * sum) : -1e30f;
        }
        barrier_lds();  // B2: biasLds visible

        f32x4 S0 = 0.f, S1 = 0.f;
        S0 = __builtin_amdgcn_mfma_f32_16x16x32_bf16(Ql, Kl0, S0, 0, 0, 0);
        S0 = __builtin_amdgcn_mfma_f32_16x16x32_bf16(Ql, Kh0, S0, 0, 0, 0);
        S0 = __builtin_amdgcn_mfma_f32_16x16x32_bf16(Qh, Kl0, S0, 0, 0, 0);
        S0 = __builtin_amdgcn_mfma_f32_16x16x32_bf16(Qh, Kh0, S0, 0, 0, 0);
        S1 = __builtin_amdgcn_mfma_f32_16x16x32_bf16(Ql, Kl1, S1, 0, 0, 0);
        S1 = __builtin_amdgcn_mfma_f32_16x16x32_bf16(Ql, Kh1, S1, 0, 0, 0);
        S1 = __builtin_amdgcn_mfma_f32_16x16x32_bf16(Qh, Kl1, S1, 0, 0, 0);
        S1 = __builtin_amdgcn_mfma_f32_16x16x32_bf16(Qh, Kh1, S1, 0, 0, 0);

        // V loads mid-body (short liveness; waiting V drains sim too, but
        // that wait sits at the O-MFMAs, just before sim's ds_write anyway)
        const size_t voA = (size_t)n15 * NK + k0 + quad * 8;
        const size_t voB = (size_t)(16 + n15) * NK + k0 + quad * 8;
        bf16x8 Vh0 = ld_bf16x8(vhb + voA), Vl0 = ld_bf16x8(vlb + voA);
        bf16x8 Vh1 = ld_bf16x8(vhb + voB), Vl1 = ld_bf16x8(vlb + voB);

        unsigned int u0[4], u1[4];
        #pragma unroll
        for (int r = 0; r < 4; ++r) {
            const int qq = quad * 4 + r;
            float s0 = S0[r] * scale + simLds[cur][wave][qq][n15]      + biasLds[qq][n15];
            float s1 = S1[r] * scale + simLds[cur][wave][qq][16 + n15] + biasLds[qq][16 + n15];

            float mx = fmaxf(s0, s1);
            #pragma unroll
            for (int off = 1; off < 16; off <<= 1) mx = fmaxf(mx, __shfl_xor(mx, off));
            const float mnew = fmaxf(m_r[r], mx);
            const float a  = __expf(m_r[r] - mnew);
            const float p0 = __expf(s0 - mnew);
            const float p1 = __expf(s1 - mnew);
            float sm = p0 + p1;
            #pragma unroll
            for (int off = 1; off < 16; off <<= 1) sm += __shfl_xor(sm, off);
            l_r[r] = l_r[r] * a + sm;
            m_r[r] = mnew;
            O0[r] *= a; O1[r] *= a;
            u0[r] = split1(p0); u1[r] = split1(p1);
        }

        // P (C-layout) -> per-wave LDS -> A-frag; two passes (hi, then lo)
        unsigned short* pw = pLds[wave];
        #pragma unroll
        for (int r = 0; r < 4; ++r) {
            const int qq = quad * 4 + r;
            pw[qq * 40 + n15]      = (unsigned short)u0[r];
            pw[qq * 40 + 16 + n15] = (unsigned short)u1[r];
        }
        bf16x8 Ph = ld_bf16x8(pw + n15 * 40 + quad * 8);
        #pragma unroll
        for (int r = 0; r < 4; ++r) {
            const int qq = quad * 4 + r;
            pw[qq * 40 + n15]      = (unsigned short)(u0[r] >> 16);
            pw[qq * 40 + 16 + n15] = (unsigned short)(u1[r] >> 16);
        }
        bf16x8 Pl = ld_bf16x8(pw + n15 * 40 + quad * 8);

        O0 = __builtin_amdgcn_mfma_f32_16x16x32_bf16(Pl, Vl0, O0, 0, 0, 0);
        O0 = __builtin_amdgcn_mfma_f32_16x16x32_bf16(Pl, Vh0, O0, 0, 0, 0);
        O0 = __builtin_amdgcn_mfma_f32_16x16x32_bf16(Ph, Vl0, O0, 0, 0, 0);
        O0 = __builtin_amdgcn_mfma_f32_16x16x32_bf16(Ph, Vh0, O0, 0, 0, 0);
        O1 = __builtin_amdgcn_mfma_f32_16x16x32_bf16(Pl, Vl1, O1, 0, 0, 0);
        O1 = __builtin_amdgcn_mfma_f32_16x16x32_bf16(Pl, Vh1, O1, 0, 0, 0);
        O1 = __builtin_amdgcn_mfma_f32_16x16x32_bf16(Ph, Vl1, O1, 0, 0, 0);
        O1 = __builtin_amdgcn_mfma_f32_16x16x32_bf16(Ph, Vh1, O1, 0, 0, 0);

        // stage tile t+1's sim into the other buffer (write-late half of T14);
        // compiler's vmcnt wait for nA/nB lands here, after a full tile in flight
        float* swn = &simLds[cur ^ 1][wave][swr][swc];
        *(f32x4*)swn       = nA;
        *(f32x4*)(swn + 4) = nB;
        mcur = mnext;
    }

    {   // peeled last tile (no prefetch)
        const int it = KT - 1;
        const int k0 = kbeg + it * 32;
        const int cur = it & 1;

        const size_t koA = (size_t)(k0 + n15) * HD + quad * 8;
        const size_t koB = (size_t)(k0 + 16 + n15) * HD + quad * 8;
        bf16x8 Kh0 = ld_bf16x8(khb + koA), Kl0 = ld_bf16x8(klb + koA);
        bf16x8 Kh1 = ld_bf16x8(khb + koB), Kl1 = ld_bf16x8(klb + koB);

        barrier_lds();
        {
            const int qq = tid >> 5;
            float sum = 0.f;
            #pragma unroll
            for (int h = 0; h < H_; ++h) sum += simLds[cur][h][qq][kk];
            biasLds[qq][kk] = ((mcur >> qq) & 1) ? (-0.125f * sum) : -1e30f;
        }
        barrier_lds();

        f32x4 S0 = 0.f, S1 = 0.f;
        S0 = __builtin_amdgcn_mfma_f32_16x16x32_bf16(Ql, Kl0, S0, 0, 0, 0);
        S0 = __builtin_amdgcn_mfma_f32_16x16x32_bf16(Ql, Kh0, S0, 0, 0, 0);
        S0 = __builtin_amdgcn_mfma_f32_16x16x32_bf16(Qh, Kl0, S0, 0, 0, 0);
        S0 = __builtin_amdgcn_mfma_f32_16x16x32_bf16(Qh, Kh0, S0, 0, 0, 0);
        S1 = __builtin_amdgcn_mfma_f32_16x16x32_bf16(Ql, Kl1, S1, 0, 0, 0);
        S1 = __builtin_amdgcn_mfma_f32_16x16x32_bf16(Ql, Kh1, S1, 0, 0, 0);
        S1 = __builtin_amdgcn_mfma_f32_16x16x32_bf16(Qh, Kl1, S1, 0, 0, 0);
        S1 = __builtin_amdgcn_mfma_f32_16x16x32_bf16(Qh, Kh1, S1, 0, 0, 0);

        const size_t voA = (size_t)n15 * NK + k0 + quad * 8;
        const size_t voB = (size_t)(16 + n15) * NK + k0 + quad * 8;
        bf16x8 Vh0 = ld_bf16x8(vhb + voA), Vl0 = ld_bf16x8(vlb + voA);
        bf16x8 Vh1 = ld_bf16x8(vhb + voB), Vl1 = ld_bf16x8(vlb + voB);

        unsigned int u0[4], u1[4];
        #pragma unroll
        for (int r = 0; r < 4; ++r) {
            const int qq = quad * 4 + r;
            float s0 = S0[r] * scale + simLds[cur][wave][qq][n15]      + biasLds[qq][n15];
            float s1 = S1[r] * scale + simLds[cur][wave][qq][16 + n15] + biasLds[qq][16 + n15];

            float mx = fmaxf(s0, s1);
            #pragma unroll
            for (int off = 1; off < 16; off <<= 1) mx = fmaxf(mx, __shfl_xor(mx, off));
            const float mnew = fmaxf(m_r[r], mx);
            const float a  = __expf(m_r[r] - mnew);
            const float p0 = __expf(s0 - mnew);
            const float p1 = __expf(s1 - mnew);
            float sm = p0 + p1;
            #pragma unroll
            for (int off = 1; off < 16; off <<= 1) sm += __shfl_xor(sm, off);
            l_r[r] = l_r[r] * a + sm;
            m_r[r] = mnew;
            O0[r] *= a; O1[r] *= a;
            u0[r] = split1(p0); u1[r] = split1(p1);
        }

        unsigned short* pw = pLds[wave];
        #pragma unroll
        for (int r = 0; r < 4; ++r) {
            const int qq = quad * 4 + r;
            pw[qq * 40 + n15]      = (unsigned short)u0[r];
            pw[qq * 40 + 16 + n15] = (unsigned short)u1[r];
        }
        bf16x8 Ph = ld_bf16x8(pw + n15 * 40 + quad * 8);
        #pragma unroll
        for (int r = 0; r < 4; ++r) {
            const int qq = quad * 4 + r;
            pw[qq * 40 + n15]      = (unsigned short)(u0[r] >> 16);
            pw[qq * 40 + 16 + n15] = (unsigned short)(u1[r] >> 16);
        }
        bf16x8 Pl = ld_bf16x8(pw + n15 * 40 + quad * 8);

        O0 = __builtin_amdgcn_mfma_f32_16x16x32_bf16(Pl, Vl0, O0, 0, 0, 0);
        O0 = __builtin_amdgcn_mfma_f32_16x16x32_bf16(Pl, Vh0, O0, 0, 0, 0);
        O0 = __builtin_amdgcn_mfma_f32_16x16x32_bf16(Ph, Vl0, O0, 0, 0, 0);
        O0 = __builtin_amdgcn_mfma_f32_16x16x32_bf16(Ph, Vh0, O0, 0, 0, 0);
        O1 = __builtin_amdgcn_mfma_f32_16x16x32_bf16(Pl, Vl1, O1, 0, 0, 0);
        O1 = __builtin_amdgcn_mfma_f32_16x16x32_bf16(Pl, Vh1, O1, 0, 0, 0);
        O1 = __builtin_amdgcn_mfma_f32_16x16x32_bf16(Ph, Vl1, O1, 0, 0, 0);
        O1 = __builtin_amdgcn_mfma_f32_16x16x32_bf16(Ph, Vh1, O1, 0, 0, 0);
    }

    // epilogue: write unnormalized partial (O, m, l)
    float* pb = part + (size_t)(((s * B_ + b) * H_ + wave) * QT_ + qt) * PART_STRIDE;
    #pragma unroll
    for (int r = 0; r < 4; ++r) {
        const int q = quad * 4 + r;
        pb[q * 32 + n15]      = O0[r];
        pb[q * 32 + 16 + n15] = O1[r];
        if (n15 == 0) {
            pb[512 + q] = m_r[r];
            pb[528 + q] = l_r[r];
        }
    }
}

// ---------------------------------------------------------------------------
// Split-K combine: merge SPLIT partials per (b,h,qt), write split-bf16 x.
// One wave per (b,h,qt): 2048 waves -> grid 512 x 256.
// ---------------------------------------------------------------------------
__global__ __launch_bounds__(256) void combine_kernel(const float* __restrict__ part,
                                                      unsigned short* __restrict__ xh,
                                                      unsigned short* __restrict__ xl)
{
    const int wid  = blockIdx.x * 4 + (threadIdx.x >> 6);  // 0..2047
    const int lane = threadIdx.x & 63;
    const int b  = wid >> 10;
    const int h  = (wid >> 7) & 7;
    const int qt = wid & 127;
    const int q  = lane >> 2;
    const int d0 = (lane & 3) * 8;

    float ms[SPLIT], ls[SPLIT];
    float mstar = -1e30f;
    #pragma unroll
    for (int s = 0; s < SPLIT; ++s) {
        const float* pb = part + (size_t)(((s * B_ + b) * H_ + h) * QT_ + qt) * PART_STRIDE;
        ms[s] = pb[512 + q];
        ls[s] = pb[528 + q];
        mstar = fmaxf(mstar, ms[s]);
    }
    f32x4 acc0 = 0.f, acc1 = 0.f;
    float lsum = 0.f;
    #pragma unroll
    for (int s = 0; s < SPLIT; ++s) {
        const float* pb = part + (size_t)(((s * B_ + b) * H_ + h) * QT_ + qt) * PART_STRIDE;
        const float w = __expf(ms[s] - mstar);
        lsum += w * ls[s];
        f32x4 o0 = *(const f32x4*)(pb + q * 32 + d0);
        f32x4 o1 = *(const f32x4*)(pb + q * 32 + d0 + 4);
        acc0 += w * o0;
        acc1 += w * o1;
    }
    const float inv = 1.0f / lsum;
    const size_t base = (size_t)(b * NQ + qt * 16 + q) * C_ + h * HD + d0;
    #pragma unroll
    for (int i = 0; i < 4; ++i) {
        unsigned int p0 = split1(acc0[i] * inv);
        unsigned int p1 = split1(acc1[i] * inv);
        xh[base + i]     = (unsigned short)p0;
        xl[base + i]     = (unsigned short)(p0 >> 16);
        xh[base + 4 + i] = (unsigned short)p1;
        xl[base + 4 + i] = (unsigned short)(p1 >> 16);
    }
}

extern "C" void kernel_launch(void* const* d_in, const int* in_sizes, int n_in,
                              void* d_out, int out_size, void* d_ws, size_t ws_size,
                              hipStream_t stream) {
    const float* query = (const float*)d_in[0];
    const float* key   = (const float*)d_in[1];
    const float* value = (const float*)d_in[2];
    // d_in[3] qpos, d_in[4] kpos: unused (rope is None)
    const int*   mask  = (const int*)d_in[5];   // bool uploaded as int32
    const float* sim   = (const float*)d_in[6];
    const float* Wq  = (const float*)d_in[7];
    const float* Wk  = (const float*)d_in[8];
    const float* Wv  = (const float*)d_in[9];
    const float* Wp  = (const float*)d_in[10];
    const float* bp  = (const float*)d_in[11];
    float* out = (float*)d_out;

    // workspace: 8 x 2MB bf16 arrays (16 MB) + partials (17.8 MB) + mask bits
    const size_t NEL = (size_t)B_ * H_ * NQ * HD;   // 1,048,576
    unsigned short* qbh = (unsigned short*)d_ws;
    unsigned short* qbl = qbh + NEL;
    unsigned short* kbh = qbl + NEL;
    unsigned short* kbl = kbh + NEL;
    unsigned short* vbh = kbl + NEL;
    unsigned short* vbl = vbh + NEL;
    unsigned short* xbh = vbl + NEL;
    unsigned short* xbl = xbh + NEL;
    float* part = (float*)(xbl + NEL);  // SPLIT*B*H*QT*544 f32 = 17.8 MB
    unsigned short* maskbW = (unsigned short*)(part
                            + (size_t)SPLIT * B_ * H_ * QT_ * PART_STRIDE);

    maskpack_kernel<<<dim3(QT_, NK / 256), 256, 0, stream>>>(mask, maskbW);
    proj_kernel<<<dim3(64, 4, 3), 256, 0, stream>>>(query, key, value, Wq, Wk, Wv,
                                                    qbh, qbl, kbh, kbl, vbh, vbl);
    attn_kernel<<<SPLIT * 256, 512, 0, stream>>>(qbh, qbl, kbh, kbl, vbh, vbl,
                                                 sim, maskbW, part);
    combine_kernel<<<512, 256, 0, stream>>>(part, xbh, xbl);
    outproj_kernel<<<dim3(64, 4), 256, 0, stream>>>(xbh, xbl, Wp, bp, out);
}

// Round 5
// 606.512 us; speedup vs baseline: 1.2133x; 1.2133x over previous
//
#include <hip/hip_runtime.h>

#define B_  2
#define NQ  2048
#define NK  2048
#define C_  256
#define H_  8
#define HD  32
#define SPLIT 4
#define KSEG (NK / SPLIT)          // 512 keys per WG
#define KT   (KSEG / 32)           // 16 tiles of 32 keys
#define QT_  (NQ / 16)             // 128 q-tiles
#define PART_STRIDE 544            // 512 O + 16 m + 16 l (f32)

typedef float f32x4 __attribute__((ext_vector_type(4)));
typedef __bf16 bf16x8 __attribute__((ext_vector_type(8)));
typedef unsigned short ushort8 __attribute__((ext_vector_type(8)));

// f32 -> bf16 round-to-nearest-even
static __device__ __forceinline__ unsigned short f2bf(float f) {
    unsigned int u = __builtin_bit_cast(unsigned int, f);
    u += 0x7FFFu + ((u >> 16) & 1u);
    return (unsigned short)(u >> 16);
}
static __device__ __forceinline__ float bf2f(unsigned short h) {
    unsigned int u = ((unsigned int)h) << 16;
    return __builtin_bit_cast(float, u);
}
// split f32 -> (hi bf16 in low 16, lo bf16 in high 16); hi+lo ~ f to 2^-19 rel
static __device__ __forceinline__ unsigned int split1(float f) {
    unsigned short h = f2bf(f);
    unsigned short l = f2bf(f - bf2f(h));
    return (unsigned int)h | ((unsigned int)l << 16);
}
static __device__ __forceinline__ bf16x8 ld_bf16x8(const unsigned short* p) {
    return __builtin_bit_cast(bf16x8, *(const ushort8*)p);
}

// raw workgroup barrier: LDS flush only, NO vmcnt drain (keeps global loads
// in flight across the barrier). sched_barrier fences per guide rule #18.
static __device__ __forceinline__ void barrier_lds() {
    __builtin_amdgcn_sched_barrier(0);
    asm volatile("s_waitcnt lgkmcnt(0)" ::: "memory");
    __builtin_amdgcn_s_barrier();
    __builtin_amdgcn_sched_barrier(0);
}

// ---------------------------------------------------------------------------
// Pack mask (int32 [NQ][NK]) into per-qtile bitmasks: maskb[qt][k] bit q = mask.
// ---------------------------------------------------------------------------
__global__ __launch_bounds__(256) void maskpack_kernel(const int* __restrict__ mask,
                                                       unsigned short* __restrict__ mb)
{
    const int qt = blockIdx.x;
    const int k  = blockIdx.y * 256 + threadIdx.x;
    unsigned int m = 0;
    #pragma unroll
    for (int r = 0; r < 16; ++r)
        m |= (mask[(size_t)(qt * 16 + r) * NK + k] ? 1u : 0u) << r;
    mb[(size_t)qt * NK + k] = (unsigned short)m;
}

// ---------------------------------------------------------------------------
// Fused Q/K/V projection GEMM (split-bf16 4-term MFMA), selected by blockIdx.z.
// z=0: Q (row layout)  z=1: K (row layout)  z=2: V (transposed layout)
// grid (64,4,3), block 256 (4 waves); tile 64x64, K-step 32.
// V epilogue: LDS-transpose then 32B coalesced stores (was 2B @4KB-stride
// scatter: ~1M scattered stores).
// ---------------------------------------------------------------------------
__global__ __launch_bounds__(256) void proj_kernel(
        const float* __restrict__ query, const float* __restrict__ key,
        const float* __restrict__ value,
        const float* __restrict__ Wq, const float* __restrict__ Wk,
        const float* __restrict__ Wv,
        unsigned short* __restrict__ qbh, unsigned short* __restrict__ qbl,
        unsigned short* __restrict__ kbh, unsigned short* __restrict__ kbl,
        unsigned short* __restrict__ vbh, unsigned short* __restrict__ vbl)
{
    __shared__ unsigned short WtH[64][40];
    __shared__ unsigned short WtL[64][40];
    __shared__ unsigned short TrH[64][80];   // [j-local][row-local], 16B-aligned rows
    __shared__ unsigned short TrL[64][80];

    const int z = blockIdx.z;
    const float* X = (z == 0) ? query : (z == 1) ? key : value;
    const float* W = (z == 0) ? Wq    : (z == 1) ? Wk  : Wv;
    unsigned short* dh = (z == 0) ? qbh : (z == 1) ? kbh : vbh;
    unsigned short* dl = (z == 0) ? qbl : (z == 1) ? kbl : vbl;
    const int vmode = (z == 2);

    const int tid  = threadIdx.x;
    const int wave = tid >> 6;
    const int lane = tid & 63;
    const int n15  = lane & 15;
    const int quad = lane >> 4;
    const int m0   = blockIdx.x * 64;
    const int j0   = blockIdx.y * 64;

    f32x4 acc[4];
    acc[0] = 0.f; acc[1] = 0.f; acc[2] = 0.f; acc[3] = 0.f;

    const int sj  = tid >> 2;
    const int skc = (tid & 3) * 8;
    const float* __restrict__ xrow = X + (size_t)(m0 + wave * 16 + n15) * C_;

    for (int k0 = 0; k0 < C_; k0 += 32) {
        ushort8 wh, wl;
        #pragma unroll
        for (int i = 0; i < 8; ++i) {
            unsigned int p = split1(W[(size_t)(k0 + skc + i) * C_ + j0 + sj]);
            wh[i] = (unsigned short)p;
            wl[i] = (unsigned short)(p >> 16);
        }
        *(ushort8*)&WtH[sj][skc] = wh;
        *(ushort8*)&WtL[sj][skc] = wl;
        __syncthreads();

        f32x4 a0 = *(const f32x4*)(xrow + k0 + quad * 8);
        f32x4 a1 = *(const f32x4*)(xrow + k0 + quad * 8 + 4);
        ushort8 ah, al;
        #pragma unroll
        for (int i = 0; i < 4; ++i) {
            unsigned int p0 = split1(a0[i]);
            unsigned int p1 = split1(a1[i]);
            ah[i]     = (unsigned short)p0;  al[i]     = (unsigned short)(p0 >> 16);
            ah[i + 4] = (unsigned short)p1;  al[i + 4] = (unsigned short)(p1 >> 16);
        }
        bf16x8 Ah = __builtin_bit_cast(bf16x8, ah);
        bf16x8 Al = __builtin_bit_cast(bf16x8, al);

        #pragma unroll
        for (int f = 0; f < 4; ++f) {
            bf16x8 Bh = ld_bf16x8(&WtH[f * 16 + n15][quad * 8]);
            bf16x8 Bl = ld_bf16x8(&WtL[f * 16 + n15][quad * 8]);
            acc[f] = __builtin_amdgcn_mfma_f32_16x16x32_bf16(Al, Bl, acc[f], 0, 0, 0);
            acc[f] = __builtin_amdgcn_mfma_f32_16x16x32_bf16(Al, Bh, acc[f], 0, 0, 0);
            acc[f] = __builtin_amdgcn_mfma_f32_16x16x32_bf16(Ah, Bl, acc[f], 0, 0, 0);
            acc[f] = __builtin_amdgcn_mfma_f32_16x16x32_bf16(Ah, Bh, acc[f], 0, 0, 0);
        }
        __syncthreads();
    }

    if (vmode) {
        // stage C-tile transposed in LDS, then coalesced 32B-run stores
        #pragma unroll
        for (int f = 0; f < 4; ++f) {
            const int jl = f * 16 + n15;
            #pragma unroll
            for (int r = 0; r < 4; ++r) {
                const int rowl = wave * 16 + quad * 4 + r;
                unsigned int p = split1(acc[f][r]);
                TrH[jl][rowl] = (unsigned short)p;
                TrL[jl][rowl] = (unsigned short)(p >> 16);
            }
        }
        __syncthreads();
        const int jl = tid >> 2, chunk = (tid & 3) * 16;
        const int j  = j0 + jl, h = j >> 5, dd = j & 31;
        const int bb = m0 >> 11;
        const size_t obase = (size_t)((bb * H_ + h) * HD + dd) * NK
                           + (m0 & 2047) + chunk;
        *(ushort8*)(dh + obase)     = *(const ushort8*)&TrH[jl][chunk];
        *(ushort8*)(dh + obase + 8) = *(const ushort8*)&TrH[jl][chunk + 8];
        *(ushort8*)(dl + obase)     = *(const ushort8*)&TrL[jl][chunk];
        *(ushort8*)(dl + obase + 8) = *(const ushort8*)&TrL[jl][chunk + 8];
    } else {
        #pragma unroll
        for (int f = 0; f < 4; ++f) {
            const int j = j0 + f * 16 + n15;
            const int h = j >> 5, dd = j & 31;
            #pragma unroll
            for (int r = 0; r < 4; ++r) {
                const int grow = m0 + wave * 16 + quad * 4 + r;
                const int b = grow >> 11, row = grow & 2047;
                unsigned int p = split1(acc[f][r]);
                size_t idx = (size_t)((b * H_ + h) * NK + row) * HD + dd;
                dh[idx] = (unsigned short)p;
                dl[idx] = (unsigned short)(p >> 16);
            }
        }
    }
}

// ---------------------------------------------------------------------------
// Output projection: out[m,j] = sum_k x[m,k]*Wp[k,j] + bp[j], f32 out.
// ---------------------------------------------------------------------------
__global__ __launch_bounds__(256) void outproj_kernel(const unsigned short* __restrict__ Xh,
                                                      const unsigned short* __restrict__ Xl,
                                                      const float* __restrict__ W,
                                                      const float* __restrict__ bias,
                                                      float* __restrict__ out)
{
    __shared__ unsigned short WtH[64][40];
    __shared__ unsigned short WtL[64][40];

    const int tid  = threadIdx.x;
    const int wave = tid >> 6;
    const int lane = tid & 63;
    const int n15  = lane & 15;
    const int quad = lane >> 4;
    const int m0   = blockIdx.x * 64;
    const int j0   = blockIdx.y * 64;

    f32x4 acc[4];
    acc[0] = 0.f; acc[1] = 0.f; acc[2] = 0.f; acc[3] = 0.f;

    const int sj  = tid >> 2;
    const int skc = (tid & 3) * 8;
    const size_t xoff = (size_t)(m0 + wave * 16 + n15) * C_;

    for (int k0 = 0; k0 < C_; k0 += 32) {
        ushort8 wh, wl;
        #pragma unroll
        for (int i = 0; i < 8; ++i) {
            unsigned int p = split1(W[(size_t)(k0 + skc + i) * C_ + j0 + sj]);
            wh[i] = (unsigned short)p;
            wl[i] = (unsigned short)(p >> 16);
        }
        *(ushort8*)&WtH[sj][skc] = wh;
        *(ushort8*)&WtL[sj][skc] = wl;
        __syncthreads();

        bf16x8 Ah = ld_bf16x8(Xh + xoff + k0 + quad * 8);
        bf16x8 Al = ld_bf16x8(Xl + xoff + k0 + quad * 8);

        #pragma unroll
        for (int f = 0; f < 4; ++f) {
            bf16x8 Bh = ld_bf16x8(&WtH[f * 16 + n15][quad * 8]);
            bf16x8 Bl = ld_bf16x8(&WtL[f * 16 + n15][quad * 8]);
            acc[f] = __builtin_amdgcn_mfma_f32_16x16x32_bf16(Al, Bl, acc[f], 0, 0, 0);
            acc[f] = __builtin_amdgcn_mfma_f32_16x16x32_bf16(Al, Bh, acc[f], 0, 0, 0);
            acc[f] = __builtin_amdgcn_mfma_f32_16x16x32_bf16(Ah, Bl, acc[f], 0, 0, 0);
            acc[f] = __builtin_amdgcn_mfma_f32_16x16x32_bf16(Ah, Bh, acc[f], 0, 0, 0);
        }
        __syncthreads();
    }

    #pragma unroll
    for (int f = 0; f < 4; ++f) {
        const int j = j0 + f * 16 + n15;
        const float bj = bias[j];
        #pragma unroll
        for (int r = 0; r < 4; ++r) {
            const int grow = m0 + wave * 16 + quad * 4 + r;
            out[(size_t)grow * C_ + j] = acc[f][r] + bj;
        }
    }
}

// ---------------------------------------------------------------------------
// Flash attention, split-K x4. grid 1024; block 512. Wave w == head w.
// sim path: REGISTER staging, issued NEWEST per tile so compiler's counted
// vmcnt waits never drain it early:
//   per-tile VMEM order: [K x4]  [sim(t+1) x2]   (mask is in LDS: prologue copy)
//   S-MFMA waits K -> vmcnt(2): sim stays in flight.
//   V issued AFTER softmax (liveness ~= P-dance only; its LDS round trip
//   covers V's L2 latency). O-MFMA waits V -> vmcnt(0): drains sim, which
//   by then is ~a full tile old (free).  ds_write sim(t+1) at tile end.
// Barriers are raw lgkm-only (no vmcnt drain ever). Register budget trimmed
// to fit the (512,6) 85-VGPR cap: R3's regression was scratch spill
// (WRITE_SIZE 312MB canary); V-late + mask-in-LDS cuts peak to ~75.
// LDS 47 KB -> 3 WGs/CU.
// ---------------------------------------------------------------------------
__global__ __launch_bounds__(512, 6) void attn_kernel(
        const unsigned short* __restrict__ qh, const unsigned short* __restrict__ ql,
        const unsigned short* __restrict__ kh, const unsigned short* __restrict__ kl,
        const unsigned short* __restrict__ vh, const unsigned short* __restrict__ vl,
        const float* __restrict__ sim, const unsigned short* __restrict__ maskb,
        float* __restrict__ part)
{
    __shared__ __align__(16) float simLds[2][H_][16][33];       // 33.8 KB (padded)
    __shared__ float biasLds[16][33];                           // 2.1 KB
    __shared__ __align__(16) unsigned short pLds[H_][16 * 40];  // 10 KB
    __shared__ unsigned short maskLds[KSEG];                    // 1 KB

    const int tid  = threadIdx.x;
    const int wave = tid >> 6;    // head
    const int lane = tid & 63;
    const int n15  = lane & 15;
    const int quad = lane >> 4;

    const int wg   = blockIdx.x;
    const int s    = wg >> 8;          // key split 0..3
    const int rem  = wg & 255;
    const int b    = rem >> 7;
    const int qt   = rem & 127;
    const int q0   = qt * 16;
    const int kbeg = s * KSEG;

    const size_t bh   = (size_t)(b * H_ + wave);
    const size_t qoff = (bh * NQ + q0 + n15) * HD + quad * 8;
    const unsigned short* khb = kh + bh * NK * HD;
    const unsigned short* klb = kl + bh * NK * HD;
    const unsigned short* vhb = vh + bh * HD * NK;
    const unsigned short* vlb = vl + bh * HD * NK;
    const unsigned short* mkb = maskb + (size_t)qt * NK + kbeg;

    // sim reg-staging mapping: lane covers row=lane>>2 (16 rows), 8 f32 at
    // col (lane&3)*8 -- 128B contiguous per 4 lanes, two dwordx4 per lane.
    const int swr = lane >> 2, swc = (lane & 3) * 8;
    const float* gsim = sim + (bh * NQ + q0 + swr) * (size_t)NK + kbeg + swc;
    const int kk = tid & 31;           // bias-phase column

    const bf16x8 Qh = ld_bf16x8(qh + qoff);
    const bf16x8 Ql = ld_bf16x8(ql + qoff);

    f32x4 O0 = 0.f, O1 = 0.f;
    float m_r[4] = {0.f, 0.f, 0.f, 0.f};   // m-floor 0 (scores << 88, safe)
    float l_r[4] = {0.f, 0.f, 0.f, 0.f};

    const float scale = 0.17677669529663687f;  // 1/sqrt(32)

    // prologue: mask segment -> LDS (one load/thread, out of the vmcnt chain
    // forever); tile-0 sim -> regs -> LDS buffer 0.
    maskLds[tid] = mkb[tid];
    {
        f32x4 pA = *(const f32x4*)gsim;
        f32x4 pB = *(const f32x4*)(gsim + 4);
        float* sw0 = &simLds[0][wave][swr][swc];
        *(f32x4*)sw0       = pA;       // compiler inserts vmcnt wait here
        *(f32x4*)(sw0 + 4) = pB;
    }

    auto tile_body = [&](int it, bool pf) {
        const int cur = it & 1;
        const int k0  = kbeg + it * 32;

        barrier_lds();  // B1: simLds[cur] (written end of prev tile) + maskLds visible

        {   // mean-over-heads + packed mask -> biasLds
            const int qq = tid >> 5;
            float sum = 0.f;
            #pragma unroll
            for (int h = 0; h < H_; ++h) sum += simLds[cur][h][qq][kk];
            const unsigned short mw = maskLds[it * 32 + kk];
            biasLds[qq][kk] = ((mw >> qq) & 1) ? (-0.125f * sum) : -1e30f;
        }
        barrier_lds();  // B2: biasLds visible

        // ---- VMEM issue: K first, then sim(t+1) NEWEST ----
        const size_t koA = (size_t)(k0 + n15) * HD + quad * 8;
        const size_t koB = (size_t)(k0 + 16 + n15) * HD + quad * 8;
        bf16x8 Kh0 = ld_bf16x8(khb + koA), Kl0 = ld_bf16x8(klb + koA);
        bf16x8 Kh1 = ld_bf16x8(khb + koB), Kl1 = ld_bf16x8(klb + koB);
        __builtin_amdgcn_sched_barrier(0);
        f32x4 nA, nB;
        if (pf) {
            nA = *(const f32x4*)(gsim + (it + 1) * 32);
            nB = *(const f32x4*)(gsim + (it + 1) * 32 + 4);
        }
        __builtin_amdgcn_sched_barrier(0);

        f32x4 S0 = 0.f, S1 = 0.f;    // K-wait here = vmcnt(2): sim in flight
        S0 = __builtin_amdgcn_mfma_f32_16x16x32_bf16(Ql, Kl0, S0, 0, 0, 0);
        S0 = __builtin_amdgcn_mfma_f32_16x16x32_bf16(Ql, Kh0, S0, 0, 0, 0);
        S0 = __builtin_amdgcn_mfma_f32_16x16x32_bf16(Qh, Kl0, S0, 0, 0, 0);
        S0 = __builtin_amdgcn_mfma_f32_16x16x32_bf16(Qh, Kh0, S0, 0, 0, 0);
        S1 = __builtin_amdgcn_mfma_f32_16x16x32_bf16(Ql, Kl1, S1, 0, 0, 0);
        S1 = __builtin_amdgcn_mfma_f32_16x16x32_bf16(Ql, Kh1, S1, 0, 0, 0);
        S1 = __builtin_amdgcn_mfma_f32_16x16x32_bf16(Qh, Kl1, S1, 0, 0, 0);
        S1 = __builtin_amdgcn_mfma_f32_16x16x32_bf16(Qh, Kh1, S1, 0, 0, 0);

        unsigned int u0[4], u1[4];
        #pragma unroll
        for (int r = 0; r < 4; ++r) {
            const int qq = quad * 4 + r;
            float s0 = S0[r] * scale + simLds[cur][wave][qq][n15]      + biasLds[qq][n15];
            float s1 = S1[r] * scale + simLds[cur][wave][qq][16 + n15] + biasLds[qq][16 + n15];

            float mx = fmaxf(s0, s1);
            #pragma unroll
            for (int off = 1; off < 16; off <<= 1) mx = fmaxf(mx, __shfl_xor(mx, off));
            const float mnew = fmaxf(m_r[r], mx);
            const float a  = __expf(m_r[r] - mnew);
            const float p0 = __expf(s0 - mnew);
            const float p1 = __expf(s1 - mnew);
            float sm = p0 + p1;
            #pragma unroll
            for (int off = 1; off < 16; off <<= 1) sm += __shfl_xor(sm, off);
            l_r[r] = l_r[r] * a + sm;
            m_r[r] = mnew;
            O0[r] *= a; O1[r] *= a;
            u0[r] = split1(p0); u1[r] = split1(p1);
        }

        // V issued post-softmax: live only through the P-dance (reg budget);
        // the P LDS round trips cover V's L2 latency.
        __builtin_amdgcn_sched_barrier(0);
        const size_t voA = (size_t)n15 * NK + k0 + quad * 8;
        const size_t voB = (size_t)(16 + n15) * NK + k0 + quad * 8;
        bf16x8 Vh0 = ld_bf16x8(vhb + voA), Vl0 = ld_bf16x8(vlb + voA);
        bf16x8 Vh1 = ld_bf16x8(vhb + voB), Vl1 = ld_bf16x8(vlb + voB);
        __builtin_amdgcn_sched_barrier(0);

        // P (C-layout) -> per-wave LDS -> A-frag; two passes (hi, then lo)
        unsigned short* pw = pLds[wave];
        #pragma unroll
        for (int r = 0; r < 4; ++r) {
            const int qq = quad * 4 + r;
            pw[qq * 40 + n15]      = (unsigned short)u0[r];
            pw[qq * 40 + 16 + n15] = (unsigned short)u1[r];
        }
        bf16x8 Ph = ld_bf16x8(pw + n15 * 40 + quad * 8);
        #pragma unroll
        for (int r = 0; r < 4; ++r) {
            const int qq = quad * 4 + r;
            pw[qq * 40 + n15]      = (unsigned short)(u0[r] >> 16);
            pw[qq * 40 + 16 + n15] = (unsigned short)(u1[r] >> 16);
        }
        bf16x8 Pl = ld_bf16x8(pw + n15 * 40 + quad * 8);

        // V-wait here = vmcnt(0): also drains sim (issued ~a tile ago, free)
        O0 = __builtin_amdgcn_mfma_f32_16x16x32_bf16(Pl, Vl0, O0, 0, 0, 0);
        O0 = __builtin_amdgcn_mfma_f32_16x16x32_bf16(Pl, Vh0, O0, 0, 0, 0);
        O0 = __builtin_amdgcn_mfma_f32_16x16x32_bf16(Ph, Vl0, O0, 0, 0, 0);
        O0 = __builtin_amdgcn_mfma_f32_16x16x32_bf16(Ph, Vh0, O0, 0, 0, 0);
        O1 = __builtin_amdgcn_mfma_f32_16x16x32_bf16(Pl, Vl1, O1, 0, 0, 0);
        O1 = __builtin_amdgcn_mfma_f32_16x16x32_bf16(Pl, Vh1, O1, 0, 0, 0);
        O1 = __builtin_amdgcn_mfma_f32_16x16x32_bf16(Ph, Vl1, O1, 0, 0, 0);
        O1 = __builtin_amdgcn_mfma_f32_16x16x32_bf16(Ph, Vh1, O1, 0, 0, 0);

        if (pf) {   // stage sim(t+1) regs -> other LDS buffer (write-late)
            float* swn = &simLds[cur ^ 1][wave][swr][swc];
            *(f32x4*)swn       = nA;
            *(f32x4*)(swn + 4) = nB;
        }
    };

    for (int it = 0; it < KT - 1; ++it) tile_body(it, true);
    tile_body(KT - 1, false);

    // epilogue: write unnormalized partial (O, m, l)
    float* pb = part + (size_t)(((s * B_ + b) * H_ + wave) * QT_ + qt) * PART_STRIDE;
    #pragma unroll
    for (int r = 0; r < 4; ++r) {
        const int q = quad * 4 + r;
        pb[q * 32 + n15]      = O0[r];
        pb[q * 32 + 16 + n15] = O1[r];
        if (n15 == 0) {
            pb[512 + q] = m_r[r];
            pb[528 + q] = l_r[r];
        }
    }
}

// ---------------------------------------------------------------------------
// Split-K combine: merge SPLIT partials per (b,h,qt), write split-bf16 x.
// One wave per (b,h,qt): 2048 waves -> grid 512 x 256.
// ---------------------------------------------------------------------------
__global__ __launch_bounds__(256) void combine_kernel(const float* __restrict__ part,
                                                      unsigned short* __restrict__ xh,
                                                      unsigned short* __restrict__ xl)
{
    const int wid  = blockIdx.x * 4 + (threadIdx.x >> 6);  // 0..2047
    const int lane = threadIdx.x & 63;
    const int b  = wid >> 10;
    const int h  = (wid >> 7) & 7;
    const int qt = wid & 127;
    const int q  = lane >> 2;
    const int d0 = (lane & 3) * 8;

    float ms[SPLIT], ls[SPLIT];
    float mstar = -1e30f;
    #pragma unroll
    for (int s = 0; s < SPLIT; ++s) {
        const float* pb = part + (size_t)(((s * B_ + b) * H_ + h) * QT_ + qt) * PART_STRIDE;
        ms[s] = pb[512 + q];
        ls[s] = pb[528 + q];
        mstar = fmaxf(mstar, ms[s]);
    }
    f32x4 acc0 = 0.f, acc1 = 0.f;
    float lsum = 0.f;
    #pragma unroll
    for (int s = 0; s < SPLIT; ++s) {
        const float* pb = part + (size_t)(((s * B_ + b) * H_ + h) * QT_ + qt) * PART_STRIDE;
        const float w = __expf(ms[s] - mstar);
        lsum += w * ls[s];
        f32x4 o0 = *(const f32x4*)(pb + q * 32 + d0);
        f32x4 o1 = *(const f32x4*)(pb + q * 32 + d0 + 4);
        acc0 += w * o0;
        acc1 += w * o1;
    }
    const float inv = 1.0f / lsum;
    const size_t base = (size_t)(b * NQ + qt * 16 + q) * C_ + h * HD + d0;
    #pragma unroll
    for (int i = 0; i < 4; ++i) {
        unsigned int p0 = split1(acc0[i] * inv);
        unsigned int p1 = split1(acc1[i] * inv);
        xh[base + i]     = (unsigned short)p0;
        xl[base + i]     = (unsigned short)(p0 >> 16);
        xh[base + 4 + i] = (unsigned short)p1;
        xl[base + 4 + i] = (unsigned short)(p1 >> 16);
    }
}

extern "C" void kernel_launch(void* const* d_in, const int* in_sizes, int n_in,
                              void* d_out, int out_size, void* d_ws, size_t ws_size,
                              hipStream_t stream) {
    const float* query = (const float*)d_in[0];
    const float* key   = (const float*)d_in[1];
    const float* value = (const float*)d_in[2];
    // d_in[3] qpos, d_in[4] kpos: unused (rope is None)
    const int*   mask  = (const int*)d_in[5];   // bool uploaded as int32
    const float* sim   = (const float*)d_in[6];
    const float* Wq  = (const float*)d_in[7];
    const float* Wk  = (const float*)d_in[8];
    const float* Wv  = (const float*)d_in[9];
    const float* Wp  = (const float*)d_in[10];
    const float* bp  = (const float*)d_in[11];
    float* out = (float*)d_out;

    // workspace: 8 x 2MB bf16 arrays (16 MB) + partials (17.8 MB) + mask bits
    const size_t NEL = (size_t)B_ * H_ * NQ * HD;   // 1,048,576
    unsigned short* qbh = (unsigned short*)d_ws;
    unsigned short* qbl = qbh + NEL;
    unsigned short* kbh = qbl + NEL;
    unsigned short* kbl = kbh + NEL;
    unsigned short* vbh = kbl + NEL;
    unsigned short* vbl = vbh + NEL;
    unsigned short* xbh = vbl + NEL;
    unsigned short* xbl = xbh + NEL;
    float* part = (float*)(xbl + NEL);  // SPLIT*B*H*QT*544 f32 = 17.8 MB
    unsigned short* maskbW = (unsigned short*)(part
                            + (size_t)SPLIT * B_ * H_ * QT_ * PART_STRIDE);

    maskpack_kernel<<<dim3(QT_, NK / 256), 256, 0, stream>>>(mask, maskbW);
    proj_kernel<<<dim3(64, 4, 3), 256, 0, stream>>>(query, key, value, Wq, Wk, Wv,
                                                    qbh, qbl, kbh, kbl, vbh, vbl);
    attn_kernel<<<SPLIT * 256, 512, 0, stream>>>(qbh, qbl, kbh, kbl, vbh, vbl,
                                                 sim, maskbW, part);
    combine_kernel<<<512, 256, 0, stream>>>(part, xbh, xbl);
    outproj_kernel<<<dim3(64, 4), 256, 0, stream>>>(xbh, xbl, Wp, bp, out);
}